// Round 1
// baseline (218.446 us; speedup 1.0000x reference)
//
#include <hip/hip_runtime.h>

#define CS   224
#define NCUT 128
#define HH   1024
#define WW   1024

// One thread per output element. out[n][ch][i][j], n<128, ch<3, i,j<224.
// Direct adaptive-avg-pool: sum x[ch][oy+lo_i : oy+hi_i][ox+lo_j : ox+hi_j] / area,
// with lo = floor(i*s/224), hi = ceil((i+1)*s/224)  (matches reference exactly).
__global__ __launch_bounds__(256) void cutouts_kernel(
    const float* __restrict__ x,
    const int*   __restrict__ sizes,
    const int*   __restrict__ oy,
    const int*   __restrict__ ox,
    float*       __restrict__ out,
    int total)
{
    int idx = blockIdx.x * 256 + threadIdx.x;
    if (idx >= total) return;

    int j  = idx % CS;
    int t  = idx / CS;
    int i  = t % CS;
    t     /= CS;
    int ch = t % 3;
    int n  = t / 3;

    int s   = sizes[n];
    int oy_ = oy[n];
    int ox_ = ox[n];

    // region bounds (exact integer floor/ceil divisions, divisor 224 is constant)
    int lo_i = (i * s) / CS;
    int hi_i = ((i + 1) * s + (CS - 1)) / CS;
    int lo_j = (j * s) / CS;
    int hi_j = ((j + 1) * s + (CS - 1)) / CS;

    int r0 = oy_ + lo_i, r1 = oy_ + hi_i;
    int c0 = ox_ + lo_j, c1 = ox_ + hi_j;

    const float* xc = x + (size_t)ch * (HH * WW);

    float sum = 0.0f;
    for (int r = r0; r < r1; ++r) {
        const float* row = xc + (size_t)r * WW;
        for (int c = c0; c < c1; ++c) {
            sum += row[c];
        }
    }

    float area = (float)((r1 - r0) * (c1 - c0));
    out[idx] = sum / area;
}

extern "C" void kernel_launch(void* const* d_in, const int* in_sizes, int n_in,
                              void* d_out, int out_size, void* d_ws, size_t ws_size,
                              hipStream_t stream) {
    const float* x     = (const float*)d_in[0];
    const int*   sizes = (const int*)d_in[1];
    const int*   oy    = (const int*)d_in[2];
    const int*   ox    = (const int*)d_in[3];
    float*       out   = (float*)d_out;

    int total  = out_size;                 // 128*3*224*224
    int blocks = (total + 255) / 256;
    cutouts_kernel<<<blocks, 256, 0, stream>>>(x, sizes, oy, ox, out, total);
}